// Round 4
// baseline (620.532 us; speedup 1.0000x reference)
//
#include <hip/hip_runtime.h>
#include <hip/hip_bf16.h>
#include <stdint.h>

#define NB 400
#define NC 151
#define DX 4096
#define DE 200
#define DP 128
#define DH 512
#define KREP 4424   // 4096 + 200 + 128
#define TAILW 328   // DE + DP
#define MPAD 416    // 13*32 rows, padded
#define SPLITK 8
#define TILES1 139  // ceil(4424/32) - GEMM1 full K
#define TILES2 132  // 4224/32     - GEMM2a label-independent K
#define SKSTRIDE 152

__device__ __forceinline__ uint32_t f2ord(float f) {
  uint32_t u = __float_as_uint(f);
  return (u & 0x80000000u) ? ~u : (u | 0x80000000u);
}

// ---------------------------------------------------------------------------
// k_embed: softmax(logits) @ obj_embed_w and pos path -> packed tail1 =
// [obj_embed(200) | pos_embed(128)]. Rows 400..415 zero (pad for float4).
// ---------------------------------------------------------------------------
__global__ __launch_bounds__(256) void k_embed(
    const float* __restrict__ logits, const float* __restrict__ obj_embed_w,
    const float* __restrict__ pos_input, const float* __restrict__ w_pos1,
    const float* __restrict__ b_pos1, const float* __restrict__ bn_gamma,
    const float* __restrict__ bn_beta, const float* __restrict__ bn_mean,
    const float* __restrict__ bn_var, const float* __restrict__ w_pos2,
    const float* __restrict__ b_pos2, float* __restrict__ tail1) {
  int r = blockIdx.x, t = threadIdx.x;
  if (r >= NB) {
    if (t < TAILW) tail1[r * TAILW + t] = 0.f;
    return;
  }
  __shared__ float p[NC];
  __shared__ float red[256];
  __shared__ float hb[32];

  float v = (t < NC) ? logits[r * NC + t] : -INFINITY;
  red[t] = v; __syncthreads();
  for (int s = 128; s > 0; s >>= 1) { if (t < s) red[t] = fmaxf(red[t], red[t + s]); __syncthreads(); }
  float m = red[0]; __syncthreads();
  float e = (t < NC) ? expf(v - m) : 0.f;
  red[t] = e; __syncthreads();
  for (int s = 128; s > 0; s >>= 1) { if (t < s) red[t] += red[t + s]; __syncthreads(); }
  float sum = red[0];
  if (t < NC) p[t] = e / sum;

  if (t < 32) {
    float acc = b_pos1[t];
    for (int k = 0; k < 9; k++) acc += pos_input[r * 9 + k] * w_pos1[k * 32 + t];
    acc = (acc - bn_mean[t]) / sqrtf(bn_var[t] + 1e-5f) * bn_gamma[t] + bn_beta[t];
    hb[t] = acc;
  }
  __syncthreads();

  if (t < DE) {
    float acc = 0.f;
    for (int k = 0; k < NC; k++) acc += p[k] * obj_embed_w[k * DE + t];
    tail1[r * TAILW + t] = acc;
  }
  if (t < DP) {
    float acc = b_pos2[t];
    for (int k = 0; k < 32; k++) acc += hb[k] * w_pos2[k * DP + t];
    tail1[r * TAILW + DE + t] = fmaxf(acc, 0.f);
  }
}

// ---------------------------------------------------------------------------
// gemm_body: split-K partial GEMM tile. A = [x(4096) | tail-segment]; tile
// 32(M)x64(N), BK=32, 2x4 microtile, register prefetch. toff selects the
// tail mapping (0: full tail1; 200: pos-only segment for GEMM2a).
// Shared tiles passed in so callers can union them with other uses.
// ---------------------------------------------------------------------------
__device__ __forceinline__ void gemm_body(
    float (*As)[36], float (*Bs)[68],
    const float* __restrict__ x, const float* __restrict__ tail,
    const float* __restrict__ w, float* __restrict__ part,
    int bid, int tiles, int toff) {
  int tid = threadIdx.x;
  int n0 = (bid & 7) * 64, m0 = ((bid >> 3) % 13) * 32;
  int z = bid / 104;
  int tbeg = (z * tiles) / SPLITK, tend = ((z + 1) * tiles) / SPLITK;
  int ty = tid >> 4, tx = tid & 15;
  int a_r = tid >> 3, a_c = (tid & 7) << 2;
  int b_r = tid >> 4, b_c = (tid & 15) << 2;
  float4 acc0 = {0, 0, 0, 0}, acc1 = {0, 0, 0, 0};

  auto loadA = [&](int t) -> float4 {
    int k = t * 32 + a_c;
    int row = m0 + a_r;
    float4 v = {0, 0, 0, 0};
    if (k < KREP) {
      if (k < DX) { if (row < NB) v = *(const float4*)&x[(size_t)row * DX + k]; }
      else v = *(const float4*)&tail[row * TAILW + toff + (k - DX)];
    }
    return v;
  };
  auto loadB = [&](int t, int roff) -> float4 {
    int k = t * 32 + b_r + roff;
    float4 v = {0, 0, 0, 0};
    if (k < KREP) v = *(const float4*)&w[(size_t)k * DH + n0 + b_c];
    return v;
  };

  float4 pa = loadA(tbeg), pb0 = loadB(tbeg, 0), pb1 = loadB(tbeg, 16);
  for (int t = tbeg; t < tend; t++) {
    __syncthreads();
    *(float4*)&As[a_r][a_c] = pa;
    *(float4*)&Bs[b_r][b_c] = pb0;
    *(float4*)&Bs[b_r + 16][b_c] = pb1;
    __syncthreads();
    if (t + 1 < tend) { pa = loadA(t + 1); pb0 = loadB(t + 1, 0); pb1 = loadB(t + 1, 16); }
#pragma unroll
    for (int k4 = 0; k4 < 8; k4++) {
      float4 a0 = *(float4*)&As[ty * 2][k4 * 4];
      float4 a1 = *(float4*)&As[ty * 2 + 1][k4 * 4];
#pragma unroll
      for (int j = 0; j < 4; j++) {
        float4 bv = *(float4*)&Bs[k4 * 4 + j][tx * 4];
        float av0 = (&a0.x)[j], av1 = (&a1.x)[j];
        acc0.x += av0 * bv.x; acc0.y += av0 * bv.y; acc0.z += av0 * bv.z; acc0.w += av0 * bv.w;
        acc1.x += av1 * bv.x; acc1.y += av1 * bv.y; acc1.z += av1 * bv.z; acc1.w += av1 * bv.w;
      }
    }
  }
  int row0 = m0 + ty * 2, col = n0 + tx * 4;
  float* base = part + (size_t)z * NB * DH;
  if (row0 < NB)     *(float4*)&base[row0 * DH + col] = acc0;
  if (row0 + 1 < NB) *(float4*)&base[(row0 + 1) * DH + col] = acc1;
}

// ---------------------------------------------------------------------------
// k_g1ov: blocks 0..831 = GEMM1 partials (A=[x|tail1], w_lin); blocks
// 832..982 = IoU>=0.5 bit matrix per class.
// ---------------------------------------------------------------------------
__global__ __launch_bounds__(256) void k_g1ov(
    const float* __restrict__ x, const float* __restrict__ tail1,
    const float* __restrict__ w_lin, float* __restrict__ part,
    const float* __restrict__ boxes, uint64_t* __restrict__ ov_bits) {
  __shared__ __align__(16) float As[32][36];
  __shared__ __align__(16) float Bs[32][68];
  int bid = blockIdx.x;
  if (bid >= 832) {
    int c = bid - 832;
    int t = threadIdx.x;
    __shared__ float4 bx[NB];
    const float4* bp4 = (const float4*)boxes;
    for (int j = t; j < NB; j += 256) bx[j] = bp4[j * NC + c];
    __syncthreads();
    int wave = t >> 6, lane = t & 63;
    for (int b = wave; b < NB; b += 4) {
      float4 A = bx[b];
      float areaA = (A.z - A.x + 1.f) * (A.w - A.y + 1.f);
      for (int chunk = 0; chunk < 7; chunk++) {
        int j = chunk * 64 + lane;
        bool ov = false;
        if (j < NB) {
          float4 B = bx[j];
          float x1 = fmaxf(A.x, B.x), y1 = fmaxf(A.y, B.y);
          float x2 = fminf(A.z, B.z), y2 = fminf(A.w, B.w);
          float iw = fmaxf(x2 - x1 + 1.f, 0.f), ih = fmaxf(y2 - y1 + 1.f, 0.f);
          float inter = iw * ih;
          float areaB = (B.z - B.x + 1.f) * (B.w - B.y + 1.f);
          ov = (inter / (areaA + areaB - inter)) >= 0.5f;
        }
        uint64_t mask = __ballot(ov);
        if (lane == 0) ov_bits[((size_t)(b * NC + c) << 3) + chunk] = mask;
      }
    }
    return;
  }
  gemm_body(As, Bs, x, tail1, w_lin, part, bid, TILES1, 0);
}

// ---------------------------------------------------------------------------
// k_dists: hidden row = sum of 8 GEMM1 partials + b_lin (in LDS, no global
// roundtrip); obj_dists = hidden @ w_out + b_out -> d_out; softmax; emit
// per-row SORTED key list (value desc, col asc), cols 1..150:
// skeys[r][rank] = (f2ord(v)<<17) | ((511-r)<<8) | col.
// ---------------------------------------------------------------------------
__global__ __launch_bounds__(256) void k_dists(
    const float* __restrict__ part, const float* __restrict__ b_lin,
    const float* __restrict__ w_out, const float* __restrict__ b_out,
    float* __restrict__ out_dists, uint64_t* __restrict__ skeys) {
  int r = blockIdx.x, t = threadIdx.x;
  __shared__ float h[DH];
  __shared__ float red[256];
  __shared__ float sval[NC];
  float s0 = b_lin[t], s1 = b_lin[t + 256];
#pragma unroll
  for (int z = 0; z < SPLITK; z++) {
    const float* pr = part + ((size_t)z * NB + r) * DH;
    s0 += pr[t]; s1 += pr[t + 256];
  }
  h[t] = s0; h[t + 256] = s1;
  __syncthreads();

  float acc = -INFINITY;
  if (t < NC) {
    acc = b_out[t];
    for (int k = 0; k < DH; k++) acc += h[k] * w_out[k * NC + t];
    out_dists[r * NC + t] = acc;
  }
  red[t] = (t < NC) ? acc : -INFINITY; __syncthreads();
  for (int s = 128; s > 0; s >>= 1) { if (t < s) red[t] = fmaxf(red[t], red[t + s]); __syncthreads(); }
  float mx = red[0]; __syncthreads();
  float e = (t < NC) ? expf(acc - mx) : 0.f;
  red[t] = e; __syncthreads();
  for (int s = 128; s > 0; s >>= 1) { if (t < s) red[t] += red[t + s]; __syncthreads(); }
  float sum = red[0];
  if (t < NC) sval[t] = e / sum;
  __syncthreads();

  if (t >= 1 && t < NC) {
    float v = sval[t];
    int rank = 0;
    for (int c2 = 1; c2 < NC; c2++) {
      float v2 = sval[c2];
      rank += (v2 > v) || (v2 == v && c2 < t);
    }
    skeys[(size_t)r * SKSTRIDE + rank] =
        ((uint64_t)f2ord(v) << 17) | ((uint64_t)(511 - r) << 8) | (uint64_t)t;
  }
}

// ---------------------------------------------------------------------------
// k_nms_g2a: block 0 = greedy NMS, top-8 speculation over 4 waves; blocks
// 1..832 = GEMM2a partials over K in [0,4224), hidden under NMS latency.
// Per round (ONE barrier): each wave publishes (a) the exact top-4 of its
// 128 rows (butterfly) and (b) the "dead mask" ballots of its 2 slots
// (dead = picked row whose cand is the -1.0 sentinel, i.e. not currently
// resurrected); both double-buffered by round parity. After the barrier all
// waves redundantly merge 16 keys -> sorted top-8, fetch the 8 ov rows,
// build the 8x8 overlap matrix via ballots, and resolve the longest valid
// prefix:
//  POSITIVE round (tk[0] value > 0.0): pick j valid iff value_j > 0.0,
//    j <= mincnt (exhaustion bound), and no i<j with c_i==c_j && ov_i[b_j].
//  TAIL round (tk[0] value == 0.0; reference is picking resurrected/
//    exhausted 0.0 entries in flat-index order): pick j valid iff
//    value_j == 0.0 exactly, j <= mincnt, and for all i<j:
//      (a) min(ov_i & deadmask) > b_j  (pick i resurrects no start-dead row
//          that would outrank b_j),
//      (b) no mid-batch resurrection: no i'<i with ov_i[b_{i'}],
//      (c) no class demotion: !(ov_i[b_j] && c_i < c_j).
//  -1 regime (all dead, tk[0] is a sentinel): napply=1 (sentinel low bits
//    encode class 0 -> reference's argmax-over--1 flat-0 behavior).
// Apply: each wave updates only its 2 slots; overlap words via intra-wave
// shfl; per (slot,pick) skip from a wave-uniform nonzero-word ballot.
// LDS state unioned with GEMM tiles: occupancy unchanged.
// ---------------------------------------------------------------------------
struct GemmSm { float As[32][36]; float Bs[32][68]; };
struct NmsSm  { uint64_t top4[2][4][4]; uint64_t dmask[2][8]; };

__global__ __launch_bounds__(256) void k_nms_g2a(
    const uint64_t* __restrict__ ov_bits, const uint64_t* __restrict__ skeys,
    int* __restrict__ labels_g, float* __restrict__ out_preds,
    const float* __restrict__ x, const float* __restrict__ tail1,
    const float* __restrict__ w_fc, float* __restrict__ part) {
  __shared__ __align__(16) union { GemmSm g; NmsSm n; } sm;
  if (blockIdx.x > 0) {
    gemm_body(sm.g.As, sm.g.Bs, x, tail1, w_fc, part, blockIdx.x - 1, TILES2, DE);
    return;
  }
  int tid = threadIdx.x, wave = tid >> 6, lane = tid & 63;
  int S0w = wave * 2;
  uint64_t cand[2];
  uint64_t supp0[2], supp1[2], supp2[2];
  int depth[2];
  bool removed[2];
  int reszmin[2];

#pragma unroll
  for (int u = 0; u < 2; u++) {
    int r = (S0w + u) * 64 + lane;
    supp0[u] = supp1[u] = supp2[u] = 0;
    depth[u] = 0; removed[u] = false; reszmin[u] = 255;
    if (r < NB) {
      cand[u] = skeys[(size_t)r * SKSTRIDE];
      labels_g[r] = 0; out_preds[r] = 0.f;
    } else cand[u] = 0;
  }

  auto cswap = [](uint64_t& a, uint64_t& b) {
    uint64_t hi = a > b ? a : b, lo = a > b ? b : a; a = hi; b = lo;
  };

  int picked = 0, rr = 0;
  while (picked < NB) {
    int pp = rr & 1; rr++;
    // ---- wave-local top-4 over my 2 slots (128 rows), butterfly ----
    uint64_t k0 = cand[0] > cand[1] ? cand[0] : cand[1];
    uint64_t k1 = cand[0] > cand[1] ? cand[1] : cand[0];
    uint64_t k2 = 0, k3 = 0;
#pragma unroll
    for (int off = 1; off < 64; off <<= 1) {
      uint64_t p0 = (uint64_t)__shfl_xor((unsigned long long)k0, off, 64);
      uint64_t p1 = (uint64_t)__shfl_xor((unsigned long long)k1, off, 64);
      uint64_t p2 = (uint64_t)__shfl_xor((unsigned long long)k2, off, 64);
      uint64_t p3 = (uint64_t)__shfl_xor((unsigned long long)k3, off, 64);
      uint64_t t0 = k0 > p3 ? k0 : p3;
      uint64_t t1 = k1 > p2 ? k1 : p2;
      uint64_t t2 = k2 > p1 ? k2 : p1;
      uint64_t t3 = k3 > p0 ? k3 : p0;
      cswap(t0, t2); cswap(t1, t3); cswap(t0, t1); cswap(t2, t3);
      k0 = t0; k1 = t1; k2 = t2; k3 = t3;
    }
    if (lane < 4) {
      uint64_t kv = (lane == 0) ? k0 : (lane == 1) ? k1 : (lane == 2) ? k2 : k3;
      sm.n.top4[pp][wave][lane] = kv;
    }
    // ---- dead-mask publish (dead = sentinel-cand picked rows) ----
    uint64_t dm0 = __ballot((uint32_t)(cand[0] >> 17) == 0x407FFFFFu);
    uint64_t dm1 = __ballot((uint32_t)(cand[1] >> 17) == 0x407FFFFFu);
    if (lane < 2) sm.n.dmask[pp][S0w + lane] = (lane == 0) ? dm0 : dm1;
    __syncthreads();   // the only barrier per round (all LDS double-buffered)

    // ---- redundant in all lanes/waves: merge 16 -> sorted top-8 ----
    uint64_t A0 = sm.n.top4[pp][0][0], A1 = sm.n.top4[pp][0][1], A2 = sm.n.top4[pp][0][2], A3 = sm.n.top4[pp][0][3];
    uint64_t B0 = sm.n.top4[pp][1][0], B1 = sm.n.top4[pp][1][1], B2 = sm.n.top4[pp][1][2], B3 = sm.n.top4[pp][1][3];
    uint64_t C0 = sm.n.top4[pp][2][0], C1 = sm.n.top4[pp][2][1], C2 = sm.n.top4[pp][2][2], C3 = sm.n.top4[pp][2][3];
    uint64_t D0 = sm.n.top4[pp][3][0], D1 = sm.n.top4[pp][3][1], D2 = sm.n.top4[pp][3][2], D3 = sm.n.top4[pp][3][3];
    // A||rev(B) bitonic -> sorted-8 desc X
    uint64_t x0 = A0, x1 = A1, x2 = A2, x3 = A3, x4 = B3, x5 = B2, x6 = B1, x7 = B0;
    cswap(x0,x4); cswap(x1,x5); cswap(x2,x6); cswap(x3,x7);
    cswap(x0,x2); cswap(x1,x3); cswap(x4,x6); cswap(x5,x7);
    cswap(x0,x1); cswap(x2,x3); cswap(x4,x5); cswap(x6,x7);
    // C||rev(D) -> sorted-8 desc Y
    uint64_t y0 = C0, y1 = C1, y2 = C2, y3 = C3, y4 = D3, y5 = D2, y6 = D1, y7 = D0;
    cswap(y0,y4); cswap(y1,y5); cswap(y2,y6); cswap(y3,y7);
    cswap(y0,y2); cswap(y1,y3); cswap(y4,y6); cswap(y5,y7);
    cswap(y0,y1); cswap(y2,y3); cswap(y4,y5); cswap(y6,y7);
    // top-8 of X,Y: bitonic max-pairs + clean
    uint64_t tk[8];
    tk[0] = x0 > y7 ? x0 : y7;  tk[1] = x1 > y6 ? x1 : y6;
    tk[2] = x2 > y5 ? x2 : y5;  tk[3] = x3 > y4 ? x3 : y4;
    tk[4] = x4 > y3 ? x4 : y3;  tk[5] = x5 > y2 ? x5 : y2;
    tk[6] = x6 > y1 ? x6 : y1;  tk[7] = x7 > y0 ? x7 : y0;
    cswap(tk[0],tk[4]); cswap(tk[1],tk[5]); cswap(tk[2],tk[6]); cswap(tk[3],tk[7]);
    cswap(tk[0],tk[2]); cswap(tk[1],tk[3]); cswap(tk[4],tk[6]); cswap(tk[5],tk[7]);
    cswap(tk[0],tk[1]); cswap(tk[2],tk[3]); cswap(tk[4],tk[5]); cswap(tk[6],tk[7]);

    // ---- exhaustion bound: count_w = #{i<8: tk[i] > wave w's 4th} ----
    int cntA = 0, cntB = 0, cntC = 0, cntD = 0;
#pragma unroll
    for (int i = 0; i < 8; i++) {
      cntA += (tk[i] > A3); cntB += (tk[i] > B3);
      cntC += (tk[i] > C3); cntD += (tk[i] > D3);
    }
    int mincnt = cntA < cntB ? cntA : cntB;
    mincnt = mincnt < cntC ? mincnt : cntC;
    mincnt = mincnt < cntD ? mincnt : cntD;

    int npick = NB - picked; if (npick > 8) npick = 8;

    // ---- fetch overlap rows: lane i*8+w -> word w of pick i (all waves) --
    int pi = lane >> 3, pw = lane & 7;
    int bsel = 0, csel = 0;
#pragma unroll
    for (int i = 0; i < 8; i++)
      if (pi == i) {
        bsel = 511 - (int)((tk[i] >> 8) & 0x1FF);
        csel = (int)(tk[i] & 0xFF);
      }
    uint64_t wv = 0;
    if (pi < npick && pw < 7)
      wv = ov_bits[(((size_t)(bsel * NC + csel)) << 3) + pw];
    uint32_t packed = ((uint32_t)bsel << 8) | (uint32_t)csel;

    uint64_t balnz_raw = __ballot(wv != 0ull);   // bit (8i+w): word w of pick i nonzero

    // ---- 8x8 conflict matrix: bit (8j+i) = pick i's row overlaps box b_j --
    uint64_t ovall = 0;
#pragma unroll
    for (int j = 0; j < 8; j++) {
      int bj = 511 - (int)((tk[j] >> 8) & 0x1FF);
      bool hit = (pw == (bj >> 6)) && ((wv >> (bj & 63)) & 1);
      uint64_t bal = __ballot(hit);
      bal |= bal >> 4; bal |= bal >> 2; bal |= bal >> 1;   // fold byte -> LSB
      uint32_t m8 = (uint32_t)(((bal & 0x0101010101010101ULL) * 0x0102040810204080ULL) >> 56);
      ovall |= (uint64_t)m8 << (8 * j);
    }

    // ---- prefix resolve ----
    uint32_t v0 = (uint32_t)(tk[0] >> 17);
    int napply = 1; bool stop = false;
    if (v0 > 0x80000000u) {
      // POSITIVE round
#pragma unroll
      for (int j = 1; j < 8; j++) {
        bool bad = (j >= npick) || (j > mincnt) ||
                   ((uint32_t)(tk[j] >> 17) <= 0x80000000u);
        int cjv = (int)(tk[j] & 0xFF);
#pragma unroll
        for (int i = 0; i < j; i++)
          bad = bad || (((int)(tk[i] & 0xFF) == cjv) && ((ovall >> (8 * j + i)) & 1));
        stop = stop || bad;
        if (!stop) napply = j + 1;
      }
    } else if (v0 == 0x80000000u) {
      // TAIL round: min resurrected start-dead row per pick
      uint64_t rm = (pw < 7) ? sm.n.dmask[pp][pw] : 0;
      uint64_t dbits = wv & rm;
      int minr = dbits ? (pw * 64 + __builtin_ctzll(dbits)) : 1024;
      {
        int o = __shfl_xor(minr, 1, 64); minr = o < minr ? o : minr;
        o = __shfl_xor(minr, 2, 64);     minr = o < minr ? o : minr;
        o = __shfl_xor(minr, 4, 64);     minr = o < minr ? o : minr;
      }
      int mr[8];
#pragma unroll
      for (int i = 0; i < 8; i++) mr[i] = __shfl(minr, i * 8, 64);
#pragma unroll
      for (int j = 1; j < 8; j++) {
        int bj = 511 - (int)((tk[j] >> 8) & 0x1FF);
        int cjv = (int)(tk[j] & 0xFF);
        bool bad = (j >= npick) || (j > mincnt) ||
                   ((uint32_t)(tk[j] >> 17) != 0x80000000u);
        // mid-batch resurrection by pick j-1 of an earlier pick's row
#pragma unroll
        for (int ip = 0; ip < 7; ip++)
          bad = bad || (ip < j - 1 && ((ovall >> (8 * ip + (j - 1))) & 1));
#pragma unroll
        for (int i = 0; i < j; i++) {
          bad = bad || (mr[i] <= bj);
          bad = bad || (((ovall >> (8 * j + i)) & 1) && ((int)(tk[i] & 0xFF) < cjv));
        }
        stop = stop || bad;
        if (!stop) napply = j + 1;
      }
    }
    // else: -1 regime (sentinel max) -> napply = 1

    uint64_t am = (napply >= 8) ? ~0ull : ((1ull << (8 * napply)) - 1);
    uint64_t balnz = balnz_raw & am;

    // ---- apply picks to my wave's 2 slots ----
#pragma unroll
    for (int u = 0; u < 2; u++) {
      int S = S0w + u;
      int r = S * 64 + lane;
      for (int i = 0; i < napply; i++) {
        int bc = __shfl((int)packed, i * 8, 64);
        int b = (bc >> 8) & 0x1FF, c = bc & 0xFF;
        bool act = ((balnz >> (i * 8 + S)) & 1) || ((b >> 6) == S);
        if (!act) continue;   // wave-uniform skip
        uint64_t owv = (uint64_t)__shfl((unsigned long long)wv, i * 8 + S, 64);
        if (r == b) {
          removed[u] = true; reszmin[u] = 255;
          cand[u] = ((uint64_t)0x407FFFFFu << 17) | ((uint64_t)(511 - r) << 8);
          labels_g[b] = c; out_preds[b] = (float)c;
        } else if ((owv >> lane) & 1) {
          if (removed[u]) {
            if (c < reszmin[u]) reszmin[u] = c;
            cand[u] = ((uint64_t)0x80000000u << 17) | ((uint64_t)(511 - r) << 8)
                      | (uint64_t)reszmin[u];
          } else {
            uint64_t bit = 1ull << (c & 63);
            if (c < 64) supp0[u] |= bit; else if (c < 128) supp1[u] |= bit; else supp2[u] |= bit;
            if ((int)(cand[u] & 0xFF) == c) {
              int d = depth[u] + 1;
              uint64_t k = 0;
              for (; d < 150; d++) {
                k = skeys[(size_t)r * SKSTRIDE + d];
                int col = (int)(k & 0xFF);
                uint64_t mm = (col < 64) ? supp0[u] : ((col < 128) ? supp1[u] : supp2[u]);
                if (!((mm >> (col & 63)) & 1)) break;
              }
              if (d >= 150)
                k = ((uint64_t)0x80000000u << 17) | ((uint64_t)(511 - r) << 8) | 1ull;
              depth[u] = d; cand[u] = k;
            }
          }
        }
      }
    }
    picked += napply;
  }
}

// ---------------------------------------------------------------------------
// k_final: edge_ctx = relu( GEMM2a-partials + emb2[labels] @ w_fc[4224:] +
// b_fc ). Grid (8 n, 13 m); 32x64 tile over K=200 with label-gathered A.
// ---------------------------------------------------------------------------
__global__ __launch_bounds__(256) void k_final(
    const float* __restrict__ emb2, const int* __restrict__ labels,
    const float* __restrict__ w_fc, const float* __restrict__ part,
    const float* __restrict__ b_fc, float* __restrict__ out_edge) {
  __shared__ __align__(16) float As[32][36];
  __shared__ __align__(16) float Bs[32][68];
  int tid = threadIdx.x;
  int n0 = blockIdx.x * 64, m0 = blockIdx.y * 32;
  int ty = tid >> 4, tx = tid & 15;
  int a_r = tid >> 3, a_c = (tid & 7) << 2;
  int b_r = tid >> 4, b_c = (tid & 15) << 2;
  float4 acc0 = {0, 0, 0, 0}, acc1 = {0, 0, 0, 0};
  int row_a = m0 + a_r;
  int lab = (row_a < NB) ? labels[row_a] : 0;

  auto loadA = [&](int t) -> float4 {
    int kk = t * 32 + a_c;
    float4 v = {0, 0, 0, 0};
    if (kk < DE && row_a < NB) v = *(const float4*)&emb2[(size_t)lab * DE + kk];
    return v;
  };
  auto loadB = [&](int t, int roff) -> float4 {
    int kk = t * 32 + b_r + roff;
    float4 v = {0, 0, 0, 0};
    if (kk < DE) v = *(const float4*)&w_fc[(size_t)(DX + DP + kk) * DH + n0 + b_c];
    return v;
  };

  float4 pa = loadA(0), pb0 = loadB(0, 0), pb1 = loadB(0, 16);
  for (int t = 0; t < 7; t++) {   // 7 tiles cover K=200 (guards handle tail)
    __syncthreads();
    *(float4*)&As[a_r][a_c] = pa;
    *(float4*)&Bs[b_r][b_c] = pb0;
    *(float4*)&Bs[b_r + 16][b_c] = pb1;
    __syncthreads();
    if (t + 1 < 7) { pa = loadA(t + 1); pb0 = loadB(t + 1, 0); pb1 = loadB(t + 1, 16); }
#pragma unroll
    for (int k4 = 0; k4 < 8; k4++) {
      float4 a0 = *(float4*)&As[ty * 2][k4 * 4];
      float4 a1 = *(float4*)&As[ty * 2 + 1][k4 * 4];
#pragma unroll
      for (int j = 0; j < 4; j++) {
        float4 bv = *(float4*)&Bs[k4 * 4 + j][tx * 4];
        float av0 = (&a0.x)[j], av1 = (&a1.x)[j];
        acc0.x += av0 * bv.x; acc0.y += av0 * bv.y; acc0.z += av0 * bv.z; acc0.w += av0 * bv.w;
        acc1.x += av1 * bv.x; acc1.y += av1 * bv.y; acc1.z += av1 * bv.z; acc1.w += av1 * bv.w;
      }
    }
  }
  int row0 = m0 + ty * 2, col = n0 + tx * 4;
#pragma unroll
  for (int z = 0; z < SPLITK; z++) {
    if (row0 < NB) {
      float4 p = *(const float4*)&part[((size_t)z * NB + row0) * DH + col];
      acc0.x += p.x; acc0.y += p.y; acc0.z += p.z; acc0.w += p.w;
    }
    if (row0 + 1 < NB) {
      float4 p = *(const float4*)&part[((size_t)z * NB + row0 + 1) * DH + col];
      acc1.x += p.x; acc1.y += p.y; acc1.z += p.z; acc1.w += p.w;
    }
  }
  float4 bv = *(const float4*)&b_fc[col];
  if (row0 < NB) {
    float4 r;
    r.x = fmaxf(acc0.x + bv.x, 0.f); r.y = fmaxf(acc0.y + bv.y, 0.f);
    r.z = fmaxf(acc0.z + bv.z, 0.f); r.w = fmaxf(acc0.w + bv.w, 0.f);
    *(float4*)&out_edge[row0 * DH + col] = r;
  }
  if (row0 + 1 < NB) {
    float4 r;
    r.x = fmaxf(acc1.x + bv.x, 0.f); r.y = fmaxf(acc1.y + bv.y, 0.f);
    r.z = fmaxf(acc1.z + bv.z, 0.f); r.w = fmaxf(acc1.w + bv.w, 0.f);
    *(float4*)&out_edge[(row0 + 1) * DH + col] = r;
  }
}

// ---------------------------------------------------------------------------
extern "C" void kernel_launch(void* const* d_in, const int* in_sizes, int n_in,
                              void* d_out, int out_size, void* d_ws, size_t ws_size,
                              hipStream_t stream) {
  const float* x            = (const float*)d_in[0];
  const float* logits       = (const float*)d_in[1];
  const float* pos_input    = (const float*)d_in[2];
  const float* boxes        = (const float*)d_in[3];
  const float* obj_embed_w  = (const float*)d_in[4];
  const float* obj_embed2_w = (const float*)d_in[5];
  const float* w_pos1       = (const float*)d_in[6];
  const float* b_pos1       = (const float*)d_in[7];
  const float* bn_gamma     = (const float*)d_in[8];
  const float* bn_beta      = (const float*)d_in[9];
  const float* bn_mean      = (const float*)d_in[10];
  const float* bn_var       = (const float*)d_in[11];
  const float* w_pos2       = (const float*)d_in[12];
  const float* b_pos2       = (const float*)d_in[13];
  const float* w_lin        = (const float*)d_in[14];
  const float* b_lin        = (const float*)d_in[15];
  const float* w_out        = (const float*)d_in[16];
  const float* b_out        = (const float*)d_in[17];
  const float* w_fc         = (const float*)d_in[18];
  const float* b_fc         = (const float*)d_in[19];

  float* ws         = (float*)d_ws;
  float* tail1      = ws;                              // 416*328 = 136448 f
  int* labels       = (int*)(tail1 + MPAD * TAILW);    // 416 ints (even offset)
  uint64_t* skeys   = (uint64_t*)(labels + MPAD);      // 400*152 u64
  uint64_t* ov_bits = skeys + (size_t)NB * SKSTRIDE;   // 400*151*8 u64
  float* part       = (float*)(ov_bits + (size_t)NB * NC * 8);  // 8*400*512 f

  float* out       = (float*)d_out;
  float* out_dists = out;                 // 400*151
  float* out_preds = out + NB * NC;       // 400
  float* out_edge  = out + NB * NC + NB;  // 400*512

  k_embed<<<MPAD, 256, 0, stream>>>(logits, obj_embed_w, pos_input, w_pos1, b_pos1,
                                    bn_gamma, bn_beta, bn_mean, bn_var, w_pos2, b_pos2,
                                    tail1);
  k_g1ov<<<983, 256, 0, stream>>>(x, tail1, w_lin, part, boxes, ov_bits);
  k_dists<<<NB, 256, 0, stream>>>(part, b_lin, w_out, b_out, out_dists, skeys);
  k_nms_g2a<<<833, 256, 0, stream>>>(ov_bits, skeys, labels, out_preds,
                                     x, tail1, w_fc, part);
  k_final<<<dim3(8, 13), 256, 0, stream>>>(obj_embed2_w, labels, w_fc, part,
                                           b_fc, out_edge);
}

// Round 5
// 566.490 us; speedup vs baseline: 1.0954x; 1.0954x over previous
//
#include <hip/hip_runtime.h>
#include <hip/hip_bf16.h>
#include <stdint.h>

#define NB 400
#define NC 151
#define DX 4096
#define DE 200
#define DP 128
#define DH 512
#define KREP 4424   // 4096 + 200 + 128
#define TAILW 328   // DE + DP
#define MPAD 416    // 13*32 rows, padded
#define SPLITK 8
#define TILES1 139  // ceil(4424/32) - GEMM1 full K
#define TILES2 132  // 4224/32     - GEMM2a label-independent K
#define SKSTRIDE 152

__device__ __forceinline__ uint32_t f2ord(float f) {
  uint32_t u = __float_as_uint(f);
  return (u & 0x80000000u) ? ~u : (u | 0x80000000u);
}

// ---------------------------------------------------------------------------
// k_embed: softmax(logits) @ obj_embed_w and pos path -> packed tail1 =
// [obj_embed(200) | pos_embed(128)]. Rows 400..415 zero (pad for float4).
// ---------------------------------------------------------------------------
__global__ __launch_bounds__(256) void k_embed(
    const float* __restrict__ logits, const float* __restrict__ obj_embed_w,
    const float* __restrict__ pos_input, const float* __restrict__ w_pos1,
    const float* __restrict__ b_pos1, const float* __restrict__ bn_gamma,
    const float* __restrict__ bn_beta, const float* __restrict__ bn_mean,
    const float* __restrict__ bn_var, const float* __restrict__ w_pos2,
    const float* __restrict__ b_pos2, float* __restrict__ tail1) {
  int r = blockIdx.x, t = threadIdx.x;
  if (r >= NB) {
    if (t < TAILW) tail1[r * TAILW + t] = 0.f;
    return;
  }
  __shared__ float p[NC];
  __shared__ float red[256];
  __shared__ float hb[32];

  float v = (t < NC) ? logits[r * NC + t] : -INFINITY;
  red[t] = v; __syncthreads();
  for (int s = 128; s > 0; s >>= 1) { if (t < s) red[t] = fmaxf(red[t], red[t + s]); __syncthreads(); }
  float m = red[0]; __syncthreads();
  float e = (t < NC) ? expf(v - m) : 0.f;
  red[t] = e; __syncthreads();
  for (int s = 128; s > 0; s >>= 1) { if (t < s) red[t] += red[t + s]; __syncthreads(); }
  float sum = red[0];
  if (t < NC) p[t] = e / sum;

  if (t < 32) {
    float acc = b_pos1[t];
    for (int k = 0; k < 9; k++) acc += pos_input[r * 9 + k] * w_pos1[k * 32 + t];
    acc = (acc - bn_mean[t]) / sqrtf(bn_var[t] + 1e-5f) * bn_gamma[t] + bn_beta[t];
    hb[t] = acc;
  }
  __syncthreads();

  if (t < DE) {
    float acc = 0.f;
    for (int k = 0; k < NC; k++) acc += p[k] * obj_embed_w[k * DE + t];
    tail1[r * TAILW + t] = acc;
  }
  if (t < DP) {
    float acc = b_pos2[t];
    for (int k = 0; k < 32; k++) acc += hb[k] * w_pos2[k * DP + t];
    tail1[r * TAILW + DE + t] = fmaxf(acc, 0.f);
  }
}

// ---------------------------------------------------------------------------
// gemm_body: split-K partial GEMM tile. A = [x(4096) | tail-segment]; tile
// 32(M)x64(N), BK=32, 2x4 microtile, register prefetch. toff selects the
// tail mapping (0: full tail1; 200: pos-only segment for GEMM2a).
// Shared tiles passed in so callers can union them with other uses.
// ---------------------------------------------------------------------------
__device__ __forceinline__ void gemm_body(
    float (*As)[36], float (*Bs)[68],
    const float* __restrict__ x, const float* __restrict__ tail,
    const float* __restrict__ w, float* __restrict__ part,
    int bid, int tiles, int toff) {
  int tid = threadIdx.x;
  int n0 = (bid & 7) * 64, m0 = ((bid >> 3) % 13) * 32;
  int z = bid / 104;
  int tbeg = (z * tiles) / SPLITK, tend = ((z + 1) * tiles) / SPLITK;
  int ty = tid >> 4, tx = tid & 15;
  int a_r = tid >> 3, a_c = (tid & 7) << 2;
  int b_r = tid >> 4, b_c = (tid & 15) << 2;
  float4 acc0 = {0, 0, 0, 0}, acc1 = {0, 0, 0, 0};

  auto loadA = [&](int t) -> float4 {
    int k = t * 32 + a_c;
    int row = m0 + a_r;
    float4 v = {0, 0, 0, 0};
    if (k < KREP) {
      if (k < DX) { if (row < NB) v = *(const float4*)&x[(size_t)row * DX + k]; }
      else v = *(const float4*)&tail[row * TAILW + toff + (k - DX)];
    }
    return v;
  };
  auto loadB = [&](int t, int roff) -> float4 {
    int k = t * 32 + b_r + roff;
    float4 v = {0, 0, 0, 0};
    if (k < KREP) v = *(const float4*)&w[(size_t)k * DH + n0 + b_c];
    return v;
  };

  float4 pa = loadA(tbeg), pb0 = loadB(tbeg, 0), pb1 = loadB(tbeg, 16);
  for (int t = tbeg; t < tend; t++) {
    __syncthreads();
    *(float4*)&As[a_r][a_c] = pa;
    *(float4*)&Bs[b_r][b_c] = pb0;
    *(float4*)&Bs[b_r + 16][b_c] = pb1;
    __syncthreads();
    if (t + 1 < tend) { pa = loadA(t + 1); pb0 = loadB(t + 1, 0); pb1 = loadB(t + 1, 16); }
#pragma unroll
    for (int k4 = 0; k4 < 8; k4++) {
      float4 a0 = *(float4*)&As[ty * 2][k4 * 4];
      float4 a1 = *(float4*)&As[ty * 2 + 1][k4 * 4];
#pragma unroll
      for (int j = 0; j < 4; j++) {
        float4 bv = *(float4*)&Bs[k4 * 4 + j][tx * 4];
        float av0 = (&a0.x)[j], av1 = (&a1.x)[j];
        acc0.x += av0 * bv.x; acc0.y += av0 * bv.y; acc0.z += av0 * bv.z; acc0.w += av0 * bv.w;
        acc1.x += av1 * bv.x; acc1.y += av1 * bv.y; acc1.z += av1 * bv.z; acc1.w += av1 * bv.w;
      }
    }
  }
  int row0 = m0 + ty * 2, col = n0 + tx * 4;
  float* base = part + (size_t)z * NB * DH;
  if (row0 < NB)     *(float4*)&base[row0 * DH + col] = acc0;
  if (row0 + 1 < NB) *(float4*)&base[(row0 + 1) * DH + col] = acc1;
}

// ---------------------------------------------------------------------------
// k_g1ov: blocks 0..831 = GEMM1 partials (A=[x|tail1], w_lin); blocks
// 832..982 = IoU>=0.5 bit matrix per class.
// ---------------------------------------------------------------------------
__global__ __launch_bounds__(256) void k_g1ov(
    const float* __restrict__ x, const float* __restrict__ tail1,
    const float* __restrict__ w_lin, float* __restrict__ part,
    const float* __restrict__ boxes, uint64_t* __restrict__ ov_bits) {
  __shared__ __align__(16) float As[32][36];
  __shared__ __align__(16) float Bs[32][68];
  int bid = blockIdx.x;
  if (bid >= 832) {
    int c = bid - 832;
    int t = threadIdx.x;
    __shared__ float4 bx[NB];
    const float4* bp4 = (const float4*)boxes;
    for (int j = t; j < NB; j += 256) bx[j] = bp4[j * NC + c];
    __syncthreads();
    int wave = t >> 6, lane = t & 63;
    for (int b = wave; b < NB; b += 4) {
      float4 A = bx[b];
      float areaA = (A.z - A.x + 1.f) * (A.w - A.y + 1.f);
      for (int chunk = 0; chunk < 7; chunk++) {
        int j = chunk * 64 + lane;
        bool ov = false;
        if (j < NB) {
          float4 B = bx[j];
          float x1 = fmaxf(A.x, B.x), y1 = fmaxf(A.y, B.y);
          float x2 = fminf(A.z, B.z), y2 = fminf(A.w, B.w);
          float iw = fmaxf(x2 - x1 + 1.f, 0.f), ih = fmaxf(y2 - y1 + 1.f, 0.f);
          float inter = iw * ih;
          float areaB = (B.z - B.x + 1.f) * (B.w - B.y + 1.f);
          ov = (inter / (areaA + areaB - inter)) >= 0.5f;
        }
        uint64_t mask = __ballot(ov);
        if (lane == 0) ov_bits[((size_t)(b * NC + c) << 3) + chunk] = mask;
      }
    }
    return;
  }
  gemm_body(As, Bs, x, tail1, w_lin, part, bid, TILES1, 0);
}

// ---------------------------------------------------------------------------
// k_dists: hidden row = sum of 8 GEMM1 partials + b_lin (in LDS, no global
// roundtrip); obj_dists = hidden @ w_out + b_out -> d_out; softmax; emit
// per-row SORTED key list (value desc, col asc), cols 1..150:
// skeys[r][rank] = (f2ord(v)<<17) | ((511-r)<<8) | col.
// ---------------------------------------------------------------------------
__global__ __launch_bounds__(256) void k_dists(
    const float* __restrict__ part, const float* __restrict__ b_lin,
    const float* __restrict__ w_out, const float* __restrict__ b_out,
    float* __restrict__ out_dists, uint64_t* __restrict__ skeys) {
  int r = blockIdx.x, t = threadIdx.x;
  __shared__ float h[DH];
  __shared__ float red[256];
  __shared__ float sval[NC];
  float s0 = b_lin[t], s1 = b_lin[t + 256];
#pragma unroll
  for (int z = 0; z < SPLITK; z++) {
    const float* pr = part + ((size_t)z * NB + r) * DH;
    s0 += pr[t]; s1 += pr[t + 256];
  }
  h[t] = s0; h[t + 256] = s1;
  __syncthreads();

  float acc = -INFINITY;
  if (t < NC) {
    acc = b_out[t];
    for (int k = 0; k < DH; k++) acc += h[k] * w_out[k * NC + t];
    out_dists[r * NC + t] = acc;
  }
  red[t] = (t < NC) ? acc : -INFINITY; __syncthreads();
  for (int s = 128; s > 0; s >>= 1) { if (t < s) red[t] = fmaxf(red[t], red[t + s]); __syncthreads(); }
  float mx = red[0]; __syncthreads();
  float e = (t < NC) ? expf(acc - mx) : 0.f;
  red[t] = e; __syncthreads();
  for (int s = 128; s > 0; s >>= 1) { if (t < s) red[t] += red[t + s]; __syncthreads(); }
  float sum = red[0];
  if (t < NC) sval[t] = e / sum;
  __syncthreads();

  if (t >= 1 && t < NC) {
    float v = sval[t];
    int rank = 0;
    for (int c2 = 1; c2 < NC; c2++) {
      float v2 = sval[c2];
      rank += (v2 > v) || (v2 == v && c2 < t);
    }
    skeys[(size_t)r * SKSTRIDE + rank] =
        ((uint64_t)f2ord(v) << 17) | ((uint64_t)(511 - r) << 8) | (uint64_t)t;
  }
}

// ---------------------------------------------------------------------------
// k_nms_g2a: block 0 = greedy NMS; blocks 1..832 = GEMM2a partials over K in
// [0,4224), hidden under NMS latency.
// POSITIVE phase (round machinery, one barrier/round): each wave publishes
// the exact top-4 of its 128 rows; all waves redundantly merge 16 -> sorted
// top-8, fetch the 8 ov rows, build the 8x8 overlap matrix via ballots, and
// apply the longest valid prefix (value>0, exhaustion bound mincnt, no
// same-class overlap conflict with an earlier pick).
// TAIL phase (serial, wave 0 only): once the global max value hits exactly
// 0.0 (monotone - positives never reappear), every alive row's candidate is
// (row, col 1) and the only other candidates are resurrected dead rows (0.0
// at min resurrection col). State = alive mask A, resurrected mask R, per
// row min col rc. Published once to LDS (one barrier), waves 1-3 retire.
// Per pick: b = min(A|R) (or box 0/class 0 in the all-dead regime), col =
// fromA ? 1 : rc[b] (or 0), fetch ov row (7xu64), T = ov & dead & ~b;
// R |= T; rc min-update; clear b; labels[b]=col. Matches reference flat
// argmax order (value desc, then row, then col).
// LDS state unioned with GEMM tiles: occupancy unchanged.
// ---------------------------------------------------------------------------
struct GemmSm { float As[32][36]; float Bs[32][68]; };
struct NmsSm  { uint64_t top4[2][4][4]; uint64_t amask[8]; uint64_t rmask[8];
                uint8_t rcol[512]; };

__global__ __launch_bounds__(256) void k_nms_g2a(
    const uint64_t* __restrict__ ov_bits, const uint64_t* __restrict__ skeys,
    int* __restrict__ labels_g, float* __restrict__ out_preds,
    const float* __restrict__ x, const float* __restrict__ tail1,
    const float* __restrict__ w_fc, float* __restrict__ part) {
  __shared__ __align__(16) union { GemmSm g; NmsSm n; } sm;
  if (blockIdx.x > 0) {
    gemm_body(sm.g.As, sm.g.Bs, x, tail1, w_fc, part, blockIdx.x - 1, TILES2, DE);
    return;
  }
  int tid = threadIdx.x, wave = tid >> 6, lane = tid & 63;
  int S0w = wave * 2;
  uint64_t cand[2];
  uint64_t supp0[2], supp1[2], supp2[2];
  int depth[2];
  bool removed[2];
  int reszmin[2];

#pragma unroll
  for (int u = 0; u < 2; u++) {
    int r = (S0w + u) * 64 + lane;
    supp0[u] = supp1[u] = supp2[u] = 0;
    depth[u] = 0; removed[u] = false; reszmin[u] = 255;
    if (r < NB) {
      cand[u] = skeys[(size_t)r * SKSTRIDE];
      labels_g[r] = 0; out_preds[r] = 0.f;
    } else cand[u] = 0;
  }

  auto cswap = [](uint64_t& a, uint64_t& b) {
    uint64_t hi = a > b ? a : b, lo = a > b ? b : a; a = hi; b = lo;
  };

  int picked = 0, rr = 0;
  while (picked < NB) {
    int pp = rr & 1; rr++;
    // ---- wave-local top-4 over my 2 slots (128 rows), butterfly ----
    uint64_t k0 = cand[0] > cand[1] ? cand[0] : cand[1];
    uint64_t k1 = cand[0] > cand[1] ? cand[1] : cand[0];
    uint64_t k2 = 0, k3 = 0;
#pragma unroll
    for (int off = 1; off < 64; off <<= 1) {
      uint64_t p0 = (uint64_t)__shfl_xor((unsigned long long)k0, off, 64);
      uint64_t p1 = (uint64_t)__shfl_xor((unsigned long long)k1, off, 64);
      uint64_t p2 = (uint64_t)__shfl_xor((unsigned long long)k2, off, 64);
      uint64_t p3 = (uint64_t)__shfl_xor((unsigned long long)k3, off, 64);
      uint64_t t0 = k0 > p3 ? k0 : p3;
      uint64_t t1 = k1 > p2 ? k1 : p2;
      uint64_t t2 = k2 > p1 ? k2 : p1;
      uint64_t t3 = k3 > p0 ? k3 : p0;
      cswap(t0, t2); cswap(t1, t3); cswap(t0, t1); cswap(t2, t3);
      k0 = t0; k1 = t1; k2 = t2; k3 = t3;
    }
    if (lane < 4) {
      uint64_t kv = (lane == 0) ? k0 : (lane == 1) ? k1 : (lane == 2) ? k2 : k3;
      sm.n.top4[pp][wave][lane] = kv;
    }
    __syncthreads();   // the only barrier per round (top4 double-buffered)

    // ---- redundant in all lanes/waves: merge 16 -> sorted top-8 ----
    uint64_t A0 = sm.n.top4[pp][0][0], A1 = sm.n.top4[pp][0][1], A2 = sm.n.top4[pp][0][2], A3 = sm.n.top4[pp][0][3];
    uint64_t B0 = sm.n.top4[pp][1][0], B1 = sm.n.top4[pp][1][1], B2 = sm.n.top4[pp][1][2], B3 = sm.n.top4[pp][1][3];
    uint64_t C0 = sm.n.top4[pp][2][0], C1 = sm.n.top4[pp][2][1], C2 = sm.n.top4[pp][2][2], C3 = sm.n.top4[pp][2][3];
    uint64_t D0 = sm.n.top4[pp][3][0], D1 = sm.n.top4[pp][3][1], D2 = sm.n.top4[pp][3][2], D3 = sm.n.top4[pp][3][3];
    // A||rev(B) bitonic -> sorted-8 desc X
    uint64_t x0 = A0, x1 = A1, x2 = A2, x3 = A3, x4 = B3, x5 = B2, x6 = B1, x7 = B0;
    cswap(x0,x4); cswap(x1,x5); cswap(x2,x6); cswap(x3,x7);
    cswap(x0,x2); cswap(x1,x3); cswap(x4,x6); cswap(x5,x7);
    cswap(x0,x1); cswap(x2,x3); cswap(x4,x5); cswap(x6,x7);
    // C||rev(D) -> sorted-8 desc Y
    uint64_t y0 = C0, y1 = C1, y2 = C2, y3 = C3, y4 = D3, y5 = D2, y6 = D1, y7 = D0;
    cswap(y0,y4); cswap(y1,y5); cswap(y2,y6); cswap(y3,y7);
    cswap(y0,y2); cswap(y1,y3); cswap(y4,y6); cswap(y5,y7);
    cswap(y0,y1); cswap(y2,y3); cswap(y4,y5); cswap(y6,y7);
    // top-8 of X,Y: bitonic max-pairs + clean
    uint64_t tk[8];
    tk[0] = x0 > y7 ? x0 : y7;  tk[1] = x1 > y6 ? x1 : y6;
    tk[2] = x2 > y5 ? x2 : y5;  tk[3] = x3 > y4 ? x3 : y4;
    tk[4] = x4 > y3 ? x4 : y3;  tk[5] = x5 > y2 ? x5 : y2;
    tk[6] = x6 > y1 ? x6 : y1;  tk[7] = x7 > y0 ? x7 : y0;
    cswap(tk[0],tk[4]); cswap(tk[1],tk[5]); cswap(tk[2],tk[6]); cswap(tk[3],tk[7]);
    cswap(tk[0],tk[2]); cswap(tk[1],tk[3]); cswap(tk[4],tk[6]); cswap(tk[5],tk[7]);
    cswap(tk[0],tk[1]); cswap(tk[2],tk[3]); cswap(tk[4],tk[5]); cswap(tk[6],tk[7]);

    // ---- tail detection: no positive candidate left -> serial mode ----
    if ((uint32_t)(tk[0] >> 17) <= 0x80000000u) break;

    // ---- exhaustion bound: count_w = #{i<8: tk[i] > wave w's 4th} ----
    int cntA = 0, cntB = 0, cntC = 0, cntD = 0;
#pragma unroll
    for (int i = 0; i < 8; i++) {
      cntA += (tk[i] > A3); cntB += (tk[i] > B3);
      cntC += (tk[i] > C3); cntD += (tk[i] > D3);
    }
    int mincnt = cntA < cntB ? cntA : cntB;
    mincnt = mincnt < cntC ? mincnt : cntC;
    mincnt = mincnt < cntD ? mincnt : cntD;

    int npick = NB - picked; if (npick > 8) npick = 8;

    // ---- fetch overlap rows: lane i*8+w -> word w of pick i (all waves) --
    int pi = lane >> 3, pw = lane & 7;
    int bsel = 0, csel = 0;
#pragma unroll
    for (int i = 0; i < 8; i++)
      if (pi == i) {
        bsel = 511 - (int)((tk[i] >> 8) & 0x1FF);
        csel = (int)(tk[i] & 0xFF);
      }
    uint64_t wv = 0;
    if (pi < npick && pw < 7)
      wv = ov_bits[(((size_t)(bsel * NC + csel)) << 3) + pw];
    uint32_t packed = ((uint32_t)bsel << 8) | (uint32_t)csel;

    uint64_t balnz_raw = __ballot(wv != 0ull);   // bit (8i+w): word w of pick i nonzero

    // ---- 8x8 conflict matrix: bit (8j+i) = pick i's row overlaps box b_j --
    uint64_t ovall = 0;
#pragma unroll
    for (int j = 0; j < 8; j++) {
      int bj = 511 - (int)((tk[j] >> 8) & 0x1FF);
      bool hit = (pw == (bj >> 6)) && ((wv >> (bj & 63)) & 1);
      uint64_t bal = __ballot(hit);
      bal |= bal >> 4; bal |= bal >> 2; bal |= bal >> 1;   // fold byte -> LSB
      uint32_t m8 = (uint32_t)(((bal & 0x0101010101010101ULL) * 0x0102040810204080ULL) >> 56);
      ovall |= (uint64_t)m8 << (8 * j);
    }

    // ---- prefix resolve (positive phase) ----
    int napply = 1; bool stop = false;
#pragma unroll
    for (int j = 1; j < 8; j++) {
      bool bad = (j >= npick) || (j > mincnt) ||
                 ((uint32_t)(tk[j] >> 17) <= 0x80000000u);
      int cjv = (int)(tk[j] & 0xFF);
#pragma unroll
      for (int i = 0; i < j; i++)
        bad = bad || (((int)(tk[i] & 0xFF) == cjv) && ((ovall >> (8 * j + i)) & 1));
      stop = stop || bad;
      if (!stop) napply = j + 1;
    }

    uint64_t am = (napply >= 8) ? ~0ull : ((1ull << (8 * napply)) - 1);
    uint64_t balnz = balnz_raw & am;

    // ---- apply picks to my wave's 2 slots ----
#pragma unroll
    for (int u = 0; u < 2; u++) {
      int S = S0w + u;
      int r = S * 64 + lane;
      for (int i = 0; i < napply; i++) {
        int bc = __shfl((int)packed, i * 8, 64);
        int b = (bc >> 8) & 0x1FF, c = bc & 0xFF;
        bool act = ((balnz >> (i * 8 + S)) & 1) || ((b >> 6) == S);
        if (!act) continue;   // wave-uniform skip
        uint64_t owv = (uint64_t)__shfl((unsigned long long)wv, i * 8 + S, 64);
        if (r == b) {
          removed[u] = true; reszmin[u] = 255;
          cand[u] = ((uint64_t)0x407FFFFFu << 17) | ((uint64_t)(511 - r) << 8);
          labels_g[b] = c; out_preds[b] = (float)c;
        } else if ((owv >> lane) & 1) {
          if (removed[u]) {
            if (c < reszmin[u]) reszmin[u] = c;
            cand[u] = ((uint64_t)0x80000000u << 17) | ((uint64_t)(511 - r) << 8)
                      | (uint64_t)reszmin[u];
          } else {
            uint64_t bit = 1ull << (c & 63);
            if (c < 64) supp0[u] |= bit; else if (c < 128) supp1[u] |= bit; else supp2[u] |= bit;
            if ((int)(cand[u] & 0xFF) == c) {
              int d = depth[u] + 1;
              uint64_t k = 0;
              for (; d < 150; d++) {
                k = skeys[(size_t)r * SKSTRIDE + d];
                int col = (int)(k & 0xFF);
                uint64_t mm = (col < 64) ? supp0[u] : ((col < 128) ? supp1[u] : supp2[u]);
                if (!((mm >> (col & 63)) & 1)) break;
              }
              if (d >= 150)
                k = ((uint64_t)0x80000000u << 17) | ((uint64_t)(511 - r) << 8) | 1ull;
              depth[u] = d; cand[u] = k;
            }
          }
        }
      }
    }
    picked += napply;
  }

  // ======== serial tail (remaining picks all have value <= 0.0) ========
  if (picked < NB) {
    // publish state: alive ballots, resurrected ballots, per-row min col
#pragma unroll
    for (int u = 0; u < 2; u++) {
      int r = (S0w + u) * 64 + lane;
      uint64_t am = __ballot(r < NB && !removed[u]);
      uint64_t rm = __ballot(removed[u] &&
                             (uint32_t)(cand[u] >> 17) == 0x80000000u);
      sm.n.rcol[(S0w + u) * 64 + lane] = (uint8_t)reszmin[u];
      if (lane == 0) { sm.n.amask[S0w + u] = am; sm.n.rmask[S0w + u] = rm; }
    }
    __syncthreads();
    if (wave != 0) return;

    uint64_t A[8], R[8];
    uint32_t rc[8];
#pragma unroll
    for (int s = 0; s < 8; s++) {
      A[s] = sm.n.amask[s];
      R[s] = sm.n.rmask[s];
      rc[s] = sm.n.rcol[s * 64 + lane];
    }

    while (picked < NB) {
      // find min row in A|R
      int b = 0, sstar = 0; bool found = false;
#pragma unroll
      for (int s = 0; s < 8; s++) {
        uint64_t cm = A[s] | R[s];
        if (!found && cm != 0ull) {
          found = true; sstar = s;
          b = s * 64 + (int)__builtin_ctzll(cm);
        }
      }
      bool fromA = false;
      uint32_t colv = 0;
      if (found) {
#pragma unroll
        for (int s = 0; s < 8; s++)
          if (s == sstar) fromA = (A[s] >> (b & 63)) & 1ull;
        if (fromA) colv = 1;
        else {
          uint32_t cv = 0;
#pragma unroll
          for (int s = 0; s < 8; s++) {
            uint32_t v = (uint32_t)__shfl((int)rc[s], b & 63, 64);
            if (s == sstar) cv = v;
          }
          colv = cv;
        }
      }
      // fetch ov row of (b, colv)
      uint64_t w = 0;
      if (lane < 7) w = ov_bits[(((size_t)(b * NC + (int)colv)) << 3) + lane];
      uint64_t W[8];
#pragma unroll
      for (int s = 0; s < 8; s++)
        W[s] = (uint64_t)__shfl((unsigned long long)w, s, 64);
      // resurrection targets: dead rows (valid & ~A) overlapping, minus b
      uint64_t T[8];
#pragma unroll
      for (int s = 0; s < 8; s++) {
        uint64_t valid = (s < 6) ? ~0ull : ((s == 6) ? 0xFFFFull : 0ull);
        T[s] = W[s] & valid & ~A[s];
      }
#pragma unroll
      for (int s = 0; s < 8; s++)
        if (s == sstar) T[s] &= ~(1ull << (b & 63));
      // clear b from its source set
#pragma unroll
      for (int s = 0; s < 8; s++)
        if (s == sstar) {
          if (fromA) A[s] &= ~(1ull << (b & 63));
          else       R[s] &= ~(1ull << (b & 63));
        }
      // resurrect + per-lane min-col update
#pragma unroll
      for (int s = 0; s < 8; s++) {
        R[s] |= T[s];
        if ((T[s] >> lane) & 1ull) rc[s] = rc[s] < colv ? rc[s] : colv;
      }
      // b died (again): reset its min-col slate
      if (!fromA) {
#pragma unroll
        for (int s = 0; s < 8; s++)
          if (s == sstar && lane == (b & 63)) rc[s] = 255;
      }
      if (lane == 0) { labels_g[b] = (int)colv; out_preds[b] = (float)colv; }
      picked++;
    }
  }
}

// ---------------------------------------------------------------------------
// k_final: edge_ctx = relu( GEMM2a-partials + emb2[labels] @ w_fc[4224:] +
// b_fc ). Grid (8 n, 13 m); 32x64 tile over K=200 with label-gathered A.
// ---------------------------------------------------------------------------
__global__ __launch_bounds__(256) void k_final(
    const float* __restrict__ emb2, const int* __restrict__ labels,
    const float* __restrict__ w_fc, const float* __restrict__ part,
    const float* __restrict__ b_fc, float* __restrict__ out_edge) {
  __shared__ __align__(16) float As[32][36];
  __shared__ __align__(16) float Bs[32][68];
  int tid = threadIdx.x;
  int n0 = blockIdx.x * 64, m0 = blockIdx.y * 32;
  int ty = tid >> 4, tx = tid & 15;
  int a_r = tid >> 3, a_c = (tid & 7) << 2;
  int b_r = tid >> 4, b_c = (tid & 15) << 2;
  float4 acc0 = {0, 0, 0, 0}, acc1 = {0, 0, 0, 0};
  int row_a = m0 + a_r;
  int lab = (row_a < NB) ? labels[row_a] : 0;

  auto loadA = [&](int t) -> float4 {
    int kk = t * 32 + a_c;
    float4 v = {0, 0, 0, 0};
    if (kk < DE && row_a < NB) v = *(const float4*)&emb2[(size_t)lab * DE + kk];
    return v;
  };
  auto loadB = [&](int t, int roff) -> float4 {
    int kk = t * 32 + b_r + roff;
    float4 v = {0, 0, 0, 0};
    if (kk < DE) v = *(const float4*)&w_fc[(size_t)(DX + DP + kk) * DH + n0 + b_c];
    return v;
  };

  float4 pa = loadA(0), pb0 = loadB(0, 0), pb1 = loadB(0, 16);
  for (int t = 0; t < 7; t++) {   // 7 tiles cover K=200 (guards handle tail)
    __syncthreads();
    *(float4*)&As[a_r][a_c] = pa;
    *(float4*)&Bs[b_r][b_c] = pb0;
    *(float4*)&Bs[b_r + 16][b_c] = pb1;
    __syncthreads();
    if (t + 1 < 7) { pa = loadA(t + 1); pb0 = loadB(t + 1, 0); pb1 = loadB(t + 1, 16); }
#pragma unroll
    for (int k4 = 0; k4 < 8; k4++) {
      float4 a0 = *(float4*)&As[ty * 2][k4 * 4];
      float4 a1 = *(float4*)&As[ty * 2 + 1][k4 * 4];
#pragma unroll
      for (int j = 0; j < 4; j++) {
        float4 bv = *(float4*)&Bs[k4 * 4 + j][tx * 4];
        float av0 = (&a0.x)[j], av1 = (&a1.x)[j];
        acc0.x += av0 * bv.x; acc0.y += av0 * bv.y; acc0.z += av0 * bv.z; acc0.w += av0 * bv.w;
        acc1.x += av1 * bv.x; acc1.y += av1 * bv.y; acc1.z += av1 * bv.z; acc1.w += av1 * bv.w;
      }
    }
  }
  int row0 = m0 + ty * 2, col = n0 + tx * 4;
#pragma unroll
  for (int z = 0; z < SPLITK; z++) {
    if (row0 < NB) {
      float4 p = *(const float4*)&part[((size_t)z * NB + row0) * DH + col];
      acc0.x += p.x; acc0.y += p.y; acc0.z += p.z; acc0.w += p.w;
    }
    if (row0 + 1 < NB) {
      float4 p = *(const float4*)&part[((size_t)z * NB + row0 + 1) * DH + col];
      acc1.x += p.x; acc1.y += p.y; acc1.z += p.z; acc1.w += p.w;
    }
  }
  float4 bv = *(const float4*)&b_fc[col];
  if (row0 < NB) {
    float4 r;
    r.x = fmaxf(acc0.x + bv.x, 0.f); r.y = fmaxf(acc0.y + bv.y, 0.f);
    r.z = fmaxf(acc0.z + bv.z, 0.f); r.w = fmaxf(acc0.w + bv.w, 0.f);
    *(float4*)&out_edge[row0 * DH + col] = r;
  }
  if (row0 + 1 < NB) {
    float4 r;
    r.x = fmaxf(acc1.x + bv.x, 0.f); r.y = fmaxf(acc1.y + bv.y, 0.f);
    r.z = fmaxf(acc1.z + bv.z, 0.f); r.w = fmaxf(acc1.w + bv.w, 0.f);
    *(float4*)&out_edge[(row0 + 1) * DH + col] = r;
  }
}

// ---------------------------------------------------------------------------
extern "C" void kernel_launch(void* const* d_in, const int* in_sizes, int n_in,
                              void* d_out, int out_size, void* d_ws, size_t ws_size,
                              hipStream_t stream) {
  const float* x            = (const float*)d_in[0];
  const float* logits       = (const float*)d_in[1];
  const float* pos_input    = (const float*)d_in[2];
  const float* boxes        = (const float*)d_in[3];
  const float* obj_embed_w  = (const float*)d_in[4];
  const float* obj_embed2_w = (const float*)d_in[5];
  const float* w_pos1       = (const float*)d_in[6];
  const float* b_pos1       = (const float*)d_in[7];
  const float* bn_gamma     = (const float*)d_in[8];
  const float* bn_beta      = (const float*)d_in[9];
  const float* bn_mean      = (const float*)d_in[10];
  const float* bn_var       = (const float*)d_in[11];
  const float* w_pos2       = (const float*)d_in[12];
  const float* b_pos2       = (const float*)d_in[13];
  const float* w_lin        = (const float*)d_in[14];
  const float* b_lin        = (const float*)d_in[15];
  const float* w_out        = (const float*)d_in[16];
  const float* b_out        = (const float*)d_in[17];
  const float* w_fc         = (const float*)d_in[18];
  const float* b_fc         = (const float*)d_in[19];

  float* ws         = (float*)d_ws;
  float* tail1      = ws;                              // 416*328 = 136448 f
  int* labels       = (int*)(tail1 + MPAD * TAILW);    // 416 ints (even offset)
  uint64_t* skeys   = (uint64_t*)(labels + MPAD);      // 400*152 u64
  uint64_t* ov_bits = skeys + (size_t)NB * SKSTRIDE;   // 400*151*8 u64
  float* part       = (float*)(ov_bits + (size_t)NB * NC * 8);  // 8*400*512 f

  float* out       = (float*)d_out;
  float* out_dists = out;                 // 400*151
  float* out_preds = out + NB * NC;       // 400
  float* out_edge  = out + NB * NC + NB;  // 400*512

  k_embed<<<MPAD, 256, 0, stream>>>(logits, obj_embed_w, pos_input, w_pos1, b_pos1,
                                    bn_gamma, bn_beta, bn_mean, bn_var, w_pos2, b_pos2,
                                    tail1);
  k_g1ov<<<983, 256, 0, stream>>>(x, tail1, w_lin, part, boxes, ov_bits);
  k_dists<<<NB, 256, 0, stream>>>(part, b_lin, w_out, b_out, out_dists, skeys);
  k_nms_g2a<<<833, 256, 0, stream>>>(ov_bits, skeys, labels, out_preds,
                                     x, tail1, w_fc, part);
  k_final<<<dim3(8, 13), 256, 0, stream>>>(obj_embed2_w, labels, w_fc, part,
                                           b_fc, out_edge);
}